// Round 7
// baseline (246.461 us; speedup 1.0000x reference)
//
#include <hip/hip_runtime.h>
#include <stdint.h>

#define BATCH  128
#define PRI    8732
#define NCLS   21
#define NPR    3
#define TOTAL  (BATCH * PRI)           // 1,117,696 = 4366 wave-assignments of 256
#define NWAVE  (TOTAL / 256)           // 4366 working waves (256 anchors each)
#define GBLK   ((NWAVE + 3) / 4)       // 1092 blocks x 4 waves (last block: 2 idle waves)

// ws layout (no memset needed - every consumed slot written unconditionally):
//   [0, KB)        uint32 keys[TOTAL]  monotone-mapped bg_loss; 0 for positives
//   [KB, ...)      float pm[NWAVE]     per-wave mask-sum partials
//   [..,  ...)     float pp[NWAVE]     per-wave pos-loss partials
//   [..,  ...)     float pr[NWAVE]     per-wave reg-loss partials
//   [..,  +1024)   double neg[BATCH]   per-row hard-negative loss sums

// ---------------------------------------------------------------------------
// k_main: coalesced + in-wave pipelined. Each wave owns 256 anchors (4 chunks
// of 64). Per chunk: COALESCED float4 loads into registers (lane-major, the
// dependency is in VGPRs so the compiler emits fine-grained vmcnt, not a
// drain), transposed to per-anchor layout through a wave-private LDS slice
// (ds_write lane-major -> ds_read stride-21; gcd(21,32)=1 -> conflict-free).
// Chunk c+1's loads are issued before chunk c's transpose+softmax, so ~5.4 KB
// per wave stays in flight across the whole compute phase. No __syncthreads.
// ---------------------------------------------------------------------------
__global__ __launch_bounds__(256)
void k_main(const float* __restrict__ conf, const float* __restrict__ pred,
            const int* __restrict__ labels, const float* __restrict__ gt,
            const float* __restrict__ mask, uint32_t* __restrict__ keys,
            float* __restrict__ pm, float* __restrict__ pp, float* __restrict__ pr)
{
  __shared__ __align__(16) float scratch[4 * 64 * NCLS];   // 4 waves x 5376 B = 21504 B
  const int tid = threadIdx.x;
  const int wv  = tid >> 6;
  const int ln  = tid & 63;
  const int gw  = blockIdx.x * 4 + wv;         // global wave id
  if (gw >= NWAVE) return;                     // wave-uniform (last block's waves 2,3)

  float*  sl  = scratch + wv * (64 * NCLS);    // this wave's private slice
  float4* sl4 = (float4*)sl;
  const long long base0 = (long long)gw * 256;

  // Prologue: prefetch chunk 0 into registers (coalesced: lane ln takes
  // float4 slots {j*64+ln}; chunk base (multiple of 64)*84B is 16B-aligned).
  float4 qa[5], qta, pda, ga;
  int laba; float mka;
  {
    const float4* s4 = (const float4*)(conf + base0 * NCLS);
    #pragma unroll
    for (int j = 0; j < 5; ++j) qa[j] = s4[j * 64 + ln];
    qta = (ln < 16) ? s4[320 + ln] : make_float4(0.f, 0.f, 0.f, 0.f);
    laba = labels[base0 + ln];
    mka  = mask[base0 + ln];
    pda  = ((const float4*)pred)[base0 + ln];
    ga   = ((const float4*)gt)[base0 + ln];
  }

  float accm = 0.f, accp = 0.f, accr = 0.f;

  #pragma unroll 1
  for (int c = 0; c < 4; ++c) {
    const long long a0 = base0 + c * 64;
    const long long a  = a0 + ln;

    // Rotate prefetch -> current (register copies; compiler renames).
    float4 q[5], qt, pd, g;
    #pragma unroll
    for (int j = 0; j < 5; ++j) q[j] = qa[j];
    qt = qta; pd = pda; g = ga;
    const int   lab = laba;
    const float mk  = mka;

    // Issue chunk c+1's coalesced loads NOW; they fly across the compute below.
    if (c + 1 < 4) {                           // wave-uniform
      const long long n0 = a0 + 64;
      const float4* s4 = (const float4*)(conf + n0 * NCLS);
      #pragma unroll
      for (int j = 0; j < 5; ++j) qa[j] = s4[j * 64 + ln];
      if (ln < 16) qta = s4[320 + ln];
      laba = labels[n0 + ln];
      mka  = mask[n0 + ln];
      pda  = ((const float4*)pred)[n0 + ln];
      ga   = ((const float4*)gt)[n0 + ln];
    }

    // Wave-synchronous LDS transpose: lane-major write, per-anchor read.
    __builtin_amdgcn_wave_barrier();           // WAR fence vs prev iter's reads
    #pragma unroll
    for (int j = 0; j < 5; ++j) sl4[j * 64 + ln] = q[j];
    if (ln < 16) sl4[320 + ln] = qt;
    __builtin_amdgcn_wave_barrier();           // writes before reads (scheduling fence)

    const float* cp = sl + ln * NCLS;          // stride 21: conflict-free
    float cv[NCLS];
    #pragma unroll
    for (int i = 0; i < NCLS; ++i) cv[i] = cp[i];

    float m = cv[0];
    #pragma unroll
    for (int i = 1; i < NCLS; ++i) m = fmaxf(m, cv[i]);
    float s = 0.f, selv = cv[0];
    #pragma unroll
    for (int i = 0; i < NCLS; ++i) {
      s += __expf(cv[i] - m);
      if (i > 0) selv = (lab == i) ? cv[i] : selv;   // cndmask, no dynamic indexing
    }
    const float lse = m + __logf(s);
    const float bg  = lse - cv[0];             // >= 0 always (lse >= max >= cv[0])
    const bool  pos = lab > 0;

    float slr = 0.f, d, ad;
    d = pd.x - g.x; ad = fabsf(d); slr += (ad < 1.f) ? 0.5f * d * d : ad - 0.5f;
    d = pd.y - g.y; ad = fabsf(d); slr += (ad < 1.f) ? 0.5f * d * d : ad - 0.5f;
    d = pd.z - g.z; ad = fabsf(d); slr += (ad < 1.f) ? 0.5f * d * d : ad - 0.5f;
    d = pd.w - g.w; ad = fabsf(d); slr += (ad < 1.f) ? 0.5f * d * d : ad - 0.5f;
    const float w = pos ? mk : 0.f;
    accm += mk;
    accp += w * (lse - selv);
    accr += w * slr;

    keys[a] = pos ? 0u : (__float_as_uint(bg) | 0x80000000u);  // monotone map; pos -> 0
  }

  // Per-wave reduction; partials to ws (no barrier, no atomics).
  #pragma unroll
  for (int o = 32; o > 0; o >>= 1) {
    accm += __shfl_down(accm, o);
    accp += __shfl_down(accp, o);
    accr += __shfl_down(accr, o);
  }
  if (ln == 0) { pm[gw] = accm; pp[gw] = accp; pr[gw] = accr; }
}

// ---------------------------------------------------------------------------
// k_select: one block (512 threads) per batch row, keys register-resident.
// Exact k-th-largest key via MSB-first search, 2 bits per round (3 candidate
// thresholds, counts monotone) -> 16 barriers. Tie-exact top-k sum.
// ---------------------------------------------------------------------------
#define SEL_T 512
#define RPT   18                               // 8732 = 512*17 + 28

__global__ __launch_bounds__(SEL_T)
void k_select(const uint32_t* __restrict__ keys, double* __restrict__ neg)
{
  __shared__ int    slots[16 * 24 + 8];        // fresh region per round
  __shared__ int    ired[8];
  __shared__ double dred[8];
  const int tid  = threadIdx.x;
  const int w    = tid >> 6;
  const int lane = tid & 63;
  const uint32_t* row = keys + (size_t)blockIdx.x * PRI;

  uint32_t kr[RPT];
  #pragma unroll
  for (int r = 0; r < 17; ++r) kr[r] = row[tid + 512 * r];
  kr[17] = (tid < 28) ? row[tid + 8704] : 0u;  // pad 0: never >= any test (tests >= 2^31)

  // np = zero-key count (pad zeros excluded by tid<28 guard).
  int zc = 0;
  #pragma unroll
  for (int r = 0; r < 17; ++r) zc += (kr[r] == 0u) ? 1 : 0;
  if (tid < 28) zc += (kr[17] == 0u) ? 1 : 0;
  #pragma unroll
  for (int o = 32; o > 0; o >>= 1) zc += __shfl_down(zc, o);
  if (lane == 0) ired[w] = zc;
  __syncthreads();
  int np = 0;
  #pragma unroll
  for (int i = 0; i < 8; ++i) np += ired[i];   // uniform

  int k = np * NPR;
  const int nneg = PRI - np;
  if (k > nneg) k = nneg;

  double result = 0.0;
  if (k > 0) {                                 // uniform branch
    uint32_t cur = 0x80000000u;                // bit31 provably set: nneg >= k
    #pragma unroll 1
    for (int bit = 30; bit >= 1; bit -= 2) {
      const int rnd = (30 - bit) >> 1;
      const uint32_t tA = cur | (3u << (bit - 1));  // bits 11
      const uint32_t tB = cur | (1u << bit);        // bits 10
      const uint32_t tC = cur | (1u << (bit - 1));  // bits 01
      int cA = 0, cB = 0, cC = 0;
      #pragma unroll
      for (int r = 0; r < RPT; ++r) {
        cA += (int)__popcll(__ballot(kr[r] >= tA));
        cB += (int)__popcll(__ballot(kr[r] >= tB));
        cC += (int)__popcll(__ballot(kr[r] >= tC));
      }
      if (lane == 0) {
        int* sl = &slots[rnd * 24];
        sl[w] = cA; sl[8 + w] = cB; sl[16 + w] = cC;
      }
      __syncthreads();
      int TA = 0, TB = 0, TC = 0;
      const int* sl = &slots[rnd * 24];
      #pragma unroll
      for (int i = 0; i < 8; ++i) { TA += sl[i]; TB += sl[8 + i]; TC += sl[16 + i]; }
      cur = (TA >= k) ? tA : (TB >= k) ? tB : (TC >= k) ? tC : cur;  // largest v: count(>=v)>=k
    }
    {                                          // final bit 0
      const uint32_t t = cur | 1u;
      int c = 0;
      #pragma unroll
      for (int r = 0; r < RPT; ++r) c += (int)__popcll(__ballot(kr[r] >= t));
      if (lane == 0) slots[16 * 24 + w] = c;
      __syncthreads();
      int tot = 0;
      #pragma unroll
      for (int i = 0; i < 8; ++i) tot += slots[16 * 24 + i];
      if (tot >= k) cur = t;                   // cur == exact k-th largest key
    }

    const float thr = __uint_as_float(cur & 0x7fffffffu);
    double ssum = 0.0;
    int g = 0;
    #pragma unroll
    for (int r = 0; r < RPT; ++r) {
      if (kr[r] > cur) { ssum += (double)__uint_as_float(kr[r] & 0x7fffffffu); ++g; }
    }
    #pragma unroll
    for (int o = 32; o > 0; o >>= 1) { ssum += __shfl_down(ssum, o); g += __shfl_down(g, o); }
    if (lane == 0) { dred[w] = ssum; ired[w] = g; }
    __syncthreads();
    if (tid == 0) {
      double tot = 0.0; int gg = 0;
      #pragma unroll
      for (int i = 0; i < 8; ++i) { tot += dred[i]; gg += ired[i]; }
      result = tot + (double)(k - gg) * (double)thr;  // tied copies at threshold
    }
  }
  if (tid == 0) neg[blockIdx.x] = result;      // unconditional: ws is poisoned
}

// ---------------------------------------------------------------------------
// k_final: reduce per-wave partials (double accumulation) + write outputs.
// ---------------------------------------------------------------------------
__global__ __launch_bounds__(256)
void k_final(const float* __restrict__ pm, const float* __restrict__ pp,
             const float* __restrict__ pr, const double* __restrict__ neg,
             float* __restrict__ out)
{
  __shared__ double red[4][4];
  const int tid = threadIdx.x, w = tid >> 6, lane = tid & 63;
  double sm = 0.0, sp = 0.0, sr = 0.0, sn = 0.0;
  for (int i = tid; i < NWAVE; i += 256) {
    sm += (double)pm[i]; sp += (double)pp[i]; sr += (double)pr[i];
  }
  if (tid < BATCH) sn = neg[tid];
  #pragma unroll
  for (int o = 32; o > 0; o >>= 1) {
    sm += __shfl_down(sm, o); sp += __shfl_down(sp, o);
    sr += __shfl_down(sr, o); sn += __shfl_down(sn, o);
  }
  if (lane == 0) { red[0][w] = sm; red[1][w] = sp; red[2][w] = sr; red[3][w] = sn; }
  __syncthreads();
  if (tid == 0) {
    double m = 0, p = 0, r = 0, n = 0;
    #pragma unroll
    for (int i = 0; i < 4; ++i) { m += red[0][i]; p += red[1][i]; r += red[2][i]; n += red[3][i]; }
    out[0] = (float)(r / m);                   // regression_loss / all_batch_pos
    out[1] = (float)((p + n) / m);             // confidence_loss / all_batch_pos
  }
}

extern "C" void kernel_launch(void* const* d_in, const int* in_sizes, int n_in,
                              void* d_out, int out_size, void* d_ws, size_t ws_size,
                              hipStream_t stream) {
  const float* conf   = (const float*)d_in[0];
  const float* pred   = (const float*)d_in[1];
  const int*   labels = (const int*)d_in[2];
  const float* gt     = (const float*)d_in[3];
  const float* mask   = (const float*)d_in[4];
  float* out = (float*)d_out;

  char* ws = (char*)d_ws;
  const size_t keys_bytes = (size_t)TOTAL * sizeof(uint32_t);  // 4,470,784 (8-aligned)
  uint32_t* keys = (uint32_t*)ws;
  float*  pm  = (float*)(ws + keys_bytes);
  float*  pp  = pm + NWAVE;
  float*  pr  = pp + NWAVE;
  double* neg = (double*)(ws + keys_bytes +
                          (((size_t)3 * NWAVE * sizeof(float) + 7) & ~(size_t)7));

  k_main<<<GBLK, 256, 0, stream>>>(conf, pred, labels, gt, mask, keys, pm, pp, pr);
  k_select<<<BATCH, SEL_T, 0, stream>>>(keys, neg);
  k_final<<<1, 256, 0, stream>>>(pm, pp, pr, neg, out);
}

// Round 8
// 217.264 us; speedup vs baseline: 1.1344x; 1.1344x over previous
//
#include <hip/hip_runtime.h>
#include <stdint.h>

#define BATCH  128
#define PRI    8732
#define NCLS   21
#define NPR    3
#define TOTAL  (BATCH * PRI)           // 1,117,696
#define CPW    2                       // chunks (of 64 anchors) per wave
#define NWAVE  (TOTAL / (64 * CPW))    // 8732 waves
#define GBLK   (NWAVE / 4)             // 2183 blocks x 4 waves (exact, no tail)

// ws layout (no memset needed - every consumed slot written unconditionally):
//   [0, KB)        uint32 keys[TOTAL]  monotone-mapped bg_loss; 0 for positives
//   [KB, ...)      float pm[NWAVE]     per-wave mask-sum partials
//   [..,  ...)     float pp[NWAVE]     per-wave pos-loss partials
//   [..,  ...)     float pr[NWAVE]     per-wave reg-loss partials
//   [..,  +1024)   double neg[BATCH]   per-row hard-negative loss sums

// ---------------------------------------------------------------------------
// k_main: the pipeline, finally with registers to run it.
// __launch_bounds__(256, 1): min 1 wave/EU -> VGPR cap 512. Every prior round
// compiled to 36-40 VGPRs and either serialized the prefetch (R2/R6) or
// spilled it to scratch (R7: +166MB WRITE). Here each wave loads BOTH of its
// 64-anchor chunks upfront (coalesced float4, ~10.8 KB in flight/wave), then
// per chunk: wave-private LDS transpose (ds_write lane-major -> ds_read
// stride-21, gcd(21,32)=1 conflict-free) + softmax. wave_barrier fences only;
// no __syncthreads, no block coupling, in-order vmcnt gives fine-grained waits.
// ---------------------------------------------------------------------------
__global__ __launch_bounds__(256, 1)
void k_main(const float* __restrict__ conf, const float* __restrict__ pred,
            const int* __restrict__ labels, const float* __restrict__ gt,
            const float* __restrict__ mask, uint32_t* __restrict__ keys,
            float* __restrict__ pm, float* __restrict__ pp, float* __restrict__ pr)
{
  __shared__ __align__(16) float scratch[4 * 64 * NCLS];   // 4 waves x 5376 B
  const int tid = threadIdx.x;
  const int wv  = tid >> 6;
  const int ln  = tid & 63;
  const int gw  = blockIdx.x * 4 + wv;         // global wave id (< NWAVE, exact grid)

  float*  sl  = scratch + wv * (64 * NCLS);    // this wave's private slice
  float4* sl4 = (float4*)sl;
  const long long base0 = (long long)gw * (64 * CPW);

  // ---- Prologue: issue ALL loads for both chunks (stay in flight together).
  // Chunk base (multiple of 64) * 84 B = n*5376 -> 16B-aligned.
  float4 q[CPW][5], qt[CPW], pd[CPW], g[CPW];
  int    lab[CPW];
  float  mk[CPW];
  #pragma unroll
  for (int c = 0; c < CPW; ++c) {
    const long long c0 = base0 + (long long)c * 64;
    const float4* s4 = (const float4*)(conf + c0 * NCLS);
    #pragma unroll
    for (int j = 0; j < 5; ++j) q[c][j] = s4[j * 64 + ln];   // coalesced
    if (ln < 16) qt[c] = s4[320 + ln];                        // 336-float4 tail
    lab[c] = labels[c0 + ln];
    mk[c]  = mask  [c0 + ln];
    pd[c]  = ((const float4*)pred)[c0 + ln];
    g[c]   = ((const float4*)gt)[c0 + ln];
  }

  float accm = 0.f, accp = 0.f, accr = 0.f;

  #pragma unroll
  for (int c = 0; c < CPW; ++c) {
    const long long a = base0 + (long long)c * 64 + ln;

    // Wave-synchronous transpose: lane-major write, per-anchor read.
    __builtin_amdgcn_wave_barrier();           // WAR fence vs prev chunk's reads
    #pragma unroll
    for (int j = 0; j < 5; ++j) sl4[j * 64 + ln] = q[c][j];
    if (ln < 16) sl4[320 + ln] = qt[c];
    __builtin_amdgcn_wave_barrier();           // writes before reads

    const float* cp = sl + ln * NCLS;          // stride 21: conflict-free
    float cv[NCLS];
    #pragma unroll
    for (int i = 0; i < NCLS; ++i) cv[i] = cp[i];

    float m = cv[0];
    #pragma unroll
    for (int i = 1; i < NCLS; ++i) m = fmaxf(m, cv[i]);
    float s = 0.f, selv = cv[0];
    #pragma unroll
    for (int i = 0; i < NCLS; ++i) {
      s += __expf(cv[i] - m);
      if (i > 0) selv = (lab[c] == i) ? cv[i] : selv;  // cndmask, no dyn indexing
    }
    const float lse = m + __logf(s);
    const float bg  = lse - cv[0];             // >= 0 always (lse >= max >= cv[0])
    const bool  pos = lab[c] > 0;

    float slr = 0.f, d, ad;
    d = pd[c].x - g[c].x; ad = fabsf(d); slr += (ad < 1.f) ? 0.5f * d * d : ad - 0.5f;
    d = pd[c].y - g[c].y; ad = fabsf(d); slr += (ad < 1.f) ? 0.5f * d * d : ad - 0.5f;
    d = pd[c].z - g[c].z; ad = fabsf(d); slr += (ad < 1.f) ? 0.5f * d * d : ad - 0.5f;
    d = pd[c].w - g[c].w; ad = fabsf(d); slr += (ad < 1.f) ? 0.5f * d * d : ad - 0.5f;
    const float w = pos ? mk[c] : 0.f;
    accm += mk[c];
    accp += w * (lse - selv);
    accr += w * slr;

    keys[a] = pos ? 0u : (__float_as_uint(bg) | 0x80000000u);  // monotone; pos -> 0
  }

  // Per-wave reduction; partials to ws (no barrier, no atomics).
  #pragma unroll
  for (int o = 32; o > 0; o >>= 1) {
    accm += __shfl_down(accm, o);
    accp += __shfl_down(accp, o);
    accr += __shfl_down(accr, o);
  }
  if (ln == 0) { pm[gw] = accm; pp[gw] = accp; pr[gw] = accr; }
}

// ---------------------------------------------------------------------------
// k_select: one block (512 threads) per batch row, keys register-resident.
// Exact k-th-largest key via MSB-first search, 2 bits per round (3 candidate
// thresholds, counts monotone) -> 16 barriers. Tie-exact top-k sum.
// ---------------------------------------------------------------------------
#define SEL_T 512
#define RPT   18                               // 8732 = 512*17 + 28

__global__ __launch_bounds__(SEL_T)
void k_select(const uint32_t* __restrict__ keys, double* __restrict__ neg)
{
  __shared__ int    slots[16 * 24 + 8];        // fresh region per round
  __shared__ int    ired[8];
  __shared__ double dred[8];
  const int tid  = threadIdx.x;
  const int w    = tid >> 6;
  const int lane = tid & 63;
  const uint32_t* row = keys + (size_t)blockIdx.x * PRI;

  uint32_t kr[RPT];
  #pragma unroll
  for (int r = 0; r < 17; ++r) kr[r] = row[tid + 512 * r];
  kr[17] = (tid < 28) ? row[tid + 8704] : 0u;  // pad 0: never >= any test (tests >= 2^31)

  // np = zero-key count (pad zeros excluded by tid<28 guard).
  int zc = 0;
  #pragma unroll
  for (int r = 0; r < 17; ++r) zc += (kr[r] == 0u) ? 1 : 0;
  if (tid < 28) zc += (kr[17] == 0u) ? 1 : 0;
  #pragma unroll
  for (int o = 32; o > 0; o >>= 1) zc += __shfl_down(zc, o);
  if (lane == 0) ired[w] = zc;
  __syncthreads();
  int np = 0;
  #pragma unroll
  for (int i = 0; i < 8; ++i) np += ired[i];   // uniform

  int k = np * NPR;
  const int nneg = PRI - np;
  if (k > nneg) k = nneg;

  double result = 0.0;
  if (k > 0) {                                 // uniform branch
    uint32_t cur = 0x80000000u;                // bit31 provably set: nneg >= k
    #pragma unroll 1
    for (int bit = 30; bit >= 1; bit -= 2) {
      const int rnd = (30 - bit) >> 1;
      const uint32_t tA = cur | (3u << (bit - 1));  // bits 11
      const uint32_t tB = cur | (1u << bit);        // bits 10
      const uint32_t tC = cur | (1u << (bit - 1));  // bits 01
      int cA = 0, cB = 0, cC = 0;
      #pragma unroll
      for (int r = 0; r < RPT; ++r) {
        cA += (int)__popcll(__ballot(kr[r] >= tA));
        cB += (int)__popcll(__ballot(kr[r] >= tB));
        cC += (int)__popcll(__ballot(kr[r] >= tC));
      }
      if (lane == 0) {
        int* sl = &slots[rnd * 24];
        sl[w] = cA; sl[8 + w] = cB; sl[16 + w] = cC;
      }
      __syncthreads();
      int TA = 0, TB = 0, TC = 0;
      const int* sl = &slots[rnd * 24];
      #pragma unroll
      for (int i = 0; i < 8; ++i) { TA += sl[i]; TB += sl[8 + i]; TC += sl[16 + i]; }
      cur = (TA >= k) ? tA : (TB >= k) ? tB : (TC >= k) ? tC : cur;  // largest v: count(>=v)>=k
    }
    {                                          // final bit 0
      const uint32_t t = cur | 1u;
      int c = 0;
      #pragma unroll
      for (int r = 0; r < RPT; ++r) c += (int)__popcll(__ballot(kr[r] >= t));
      if (lane == 0) slots[16 * 24 + w] = c;
      __syncthreads();
      int tot = 0;
      #pragma unroll
      for (int i = 0; i < 8; ++i) tot += slots[16 * 24 + i];
      if (tot >= k) cur = t;                   // cur == exact k-th largest key
    }

    const float thr = __uint_as_float(cur & 0x7fffffffu);
    double ssum = 0.0;
    int g = 0;
    #pragma unroll
    for (int r = 0; r < RPT; ++r) {
      if (kr[r] > cur) { ssum += (double)__uint_as_float(kr[r] & 0x7fffffffu); ++g; }
    }
    #pragma unroll
    for (int o = 32; o > 0; o >>= 1) { ssum += __shfl_down(ssum, o); g += __shfl_down(g, o); }
    if (lane == 0) { dred[w] = ssum; ired[w] = g; }
    __syncthreads();
    if (tid == 0) {
      double tot = 0.0; int gg = 0;
      #pragma unroll
      for (int i = 0; i < 8; ++i) { tot += dred[i]; gg += ired[i]; }
      result = tot + (double)(k - gg) * (double)thr;  // tied copies at threshold
    }
  }
  if (tid == 0) neg[blockIdx.x] = result;      // unconditional: ws is poisoned
}

// ---------------------------------------------------------------------------
// k_final: reduce per-wave partials (double accumulation) + write outputs.
// ---------------------------------------------------------------------------
__global__ __launch_bounds__(256)
void k_final(const float* __restrict__ pm, const float* __restrict__ pp,
             const float* __restrict__ pr, const double* __restrict__ neg,
             float* __restrict__ out)
{
  __shared__ double red[4][4];
  const int tid = threadIdx.x, w = tid >> 6, lane = tid & 63;
  double sm = 0.0, sp = 0.0, sr = 0.0, sn = 0.0;
  for (int i = tid; i < NWAVE; i += 256) {
    sm += (double)pm[i]; sp += (double)pp[i]; sr += (double)pr[i];
  }
  if (tid < BATCH) sn = neg[tid];
  #pragma unroll
  for (int o = 32; o > 0; o >>= 1) {
    sm += __shfl_down(sm, o); sp += __shfl_down(sp, o);
    sr += __shfl_down(sr, o); sn += __shfl_down(sn, o);
  }
  if (lane == 0) { red[0][w] = sm; red[1][w] = sp; red[2][w] = sr; red[3][w] = sn; }
  __syncthreads();
  if (tid == 0) {
    double m = 0, p = 0, r = 0, n = 0;
    #pragma unroll
    for (int i = 0; i < 4; ++i) { m += red[0][i]; p += red[1][i]; r += red[2][i]; n += red[3][i]; }
    out[0] = (float)(r / m);                   // regression_loss / all_batch_pos
    out[1] = (float)((p + n) / m);             // confidence_loss / all_batch_pos
  }
}

extern "C" void kernel_launch(void* const* d_in, const int* in_sizes, int n_in,
                              void* d_out, int out_size, void* d_ws, size_t ws_size,
                              hipStream_t stream) {
  const float* conf   = (const float*)d_in[0];
  const float* pred   = (const float*)d_in[1];
  const int*   labels = (const int*)d_in[2];
  const float* gt     = (const float*)d_in[3];
  const float* mask   = (const float*)d_in[4];
  float* out = (float*)d_out;

  char* ws = (char*)d_ws;
  const size_t keys_bytes = (size_t)TOTAL * sizeof(uint32_t);  // 4,470,784 (8-aligned)
  uint32_t* keys = (uint32_t*)ws;
  float*  pm  = (float*)(ws + keys_bytes);
  float*  pp  = pm + NWAVE;
  float*  pr  = pp + NWAVE;
  double* neg = (double*)(ws + keys_bytes +
                          (((size_t)3 * NWAVE * sizeof(float) + 7) & ~(size_t)7));

  k_main<<<GBLK, 256, 0, stream>>>(conf, pred, labels, gt, mask, keys, pm, pp, pr);
  k_select<<<BATCH, SEL_T, 0, stream>>>(keys, neg);
  k_final<<<1, 256, 0, stream>>>(pm, pp, pr, neg, out);
}

// Round 9
// 197.962 us; speedup vs baseline: 1.2450x; 1.0975x over previous
//
#include <hip/hip_runtime.h>
#include <stdint.h>

#define BATCH  128
#define PRI    8732
#define NCLS   21
#define NPR    3
#define TOTAL  (BATCH * PRI)           // 1,117,696
#define CPW    4                       // chunks (64 anchors) per wave
#define NWAVE  (TOTAL / (64 * CPW))    // 4366 waves
#define GBLK   ((NWAVE + 3) / 4)       // 1092 blocks x 4 waves (last: 2 idle waves)

// ws layout (no memset needed - every consumed slot written unconditionally):
//   [0, KB)        uint32 keys[TOTAL]  monotone-mapped bg_loss; 0 for positives
//   [KB, ...)      float pm[NWAVE]     per-wave mask-sum partials
//   [..,  ...)     float pp[NWAVE]     per-wave pos-loss partials
//   [..,  ...)     float pr[NWAVE]     per-wave reg-loss partials
//   [..,  +1024)   double neg[BATCH]   per-row hard-negative loss sums

typedef const __attribute__((address_space(1))) void gv_t;
typedef __attribute__((address_space(3))) void lv_t;

// One 64-anchor chunk of conf (1344 floats, contiguous, anchor-major) staged
// HBM->LDS by DMA: 5x16B + 1x4B per lane = 6 vmcnt ops, ZERO data VGPRs.
// The compiler cannot sink or spill this pipeline (R2/R6/R8 sank register
// prefetch to 36 VGPRs; R7 spilled it at +166MB scratch traffic).
__device__ __forceinline__ void dma_chunk(const float* __restrict__ conf,
                                          float* dst, long long c0, int ln) {
  const float*  src = conf + c0 * NCLS;          // c0 mult of 64 -> 16B-aligned
  const float4* s4  = (const float4*)src;
  float4*       d4  = (float4*)dst;
  #pragma unroll
  for (int j = 0; j < 5; ++j)
    __builtin_amdgcn_global_load_lds((gv_t*)(s4 + j * 64 + ln),
                                     (lv_t*)(d4 + j * 64), 16, 0, 0);
  __builtin_amdgcn_global_load_lds((gv_t*)(src + 1280 + ln),
                                   (lv_t*)(dst + 1280), 4, 0, 0);
}

__device__ __forceinline__ void do_chunk(const float* sl, int ln, long long a,
                                         int lab, float mk,
                                         const float4* __restrict__ pred4,
                                         const float4* __restrict__ gt4,
                                         uint32_t* __restrict__ keys,
                                         float& accm, float& accp, float& accr)
{
  const float* cp = sl + ln * NCLS;              // stride 21: gcd(21,32)=1, free
  float cv[NCLS];
  #pragma unroll
  for (int i = 0; i < NCLS; ++i) cv[i] = cp[i];
  float m = cv[0];
  #pragma unroll
  for (int i = 1; i < NCLS; ++i) m = fmaxf(m, cv[i]);
  float s = 0.f, selv = cv[0];
  #pragma unroll
  for (int i = 0; i < NCLS; ++i) {
    s += __expf(cv[i] - m);
    if (i > 0) selv = (lab == i) ? cv[i] : selv; // cndmask, no dynamic indexing
  }
  const float lse = m + __logf(s);
  const float bg  = lse - cv[0];                 // >= 0 (lse >= max >= cv[0])
  const bool  pos = lab > 0;
  accm += mk;
  if (pos) {                                     // ~3% of anchors: loads stay rare
    accp += mk * (lse - selv);
    const float4 pd = pred4[a];
    const float4 g  = gt4[a];
    float sl1 = 0.f, d, ad;
    d = pd.x - g.x; ad = fabsf(d); sl1 += (ad < 1.f) ? 0.5f * d * d : ad - 0.5f;
    d = pd.y - g.y; ad = fabsf(d); sl1 += (ad < 1.f) ? 0.5f * d * d : ad - 0.5f;
    d = pd.z - g.z; ad = fabsf(d); sl1 += (ad < 1.f) ? 0.5f * d * d : ad - 0.5f;
    d = pd.w - g.w; ad = fabsf(d); sl1 += (ad < 1.f) ? 0.5f * d * d : ad - 0.5f;
    accr += mk * sl1;
  }
  keys[a] = pos ? 0u : (__float_as_uint(bg) | 0x80000000u);  // monotone; pos -> 0
}

// ---------------------------------------------------------------------------
// k_main: wave-private rolling DMA double-buffer, manual vmcnt scheduling.
// Per wave: 4 chunks, 2 LDS buffers ping-pong. VMEM issue groups of 8
// (6 DMA + labels + mask); waits are vmcnt(8),8,8,0 - i.e. the next chunk's
// 5.4 KB is ALWAYS in flight across the current chunk's softmax (the AITER
// never-wait-to-zero pattern). No __syncthreads, no wave_barrier, no atomics.
// 43008 B LDS -> 3 blocks/CU = 12 self-paced waves overlapping on top.
// ---------------------------------------------------------------------------
__global__ __launch_bounds__(256)
void k_main(const float* __restrict__ conf, const float* __restrict__ pred,
            const int* __restrict__ labels, const float* __restrict__ gt,
            const float* __restrict__ mask, uint32_t* __restrict__ keys,
            float* __restrict__ pm, float* __restrict__ pp, float* __restrict__ pr)
{
  __shared__ __align__(16) float scratch[2][4][64 * NCLS];   // 43008 B
  const int tid = threadIdx.x;
  const int wv  = tid >> 6;
  const int ln  = tid & 63;
  const int gw  = blockIdx.x * 4 + wv;
  if (gw >= NWAVE) return;                       // wave-uniform; no barriers exist

  const long long b0 = (long long)gw * (64 * CPW);
  const float4* pred4 = (const float4*)pred;
  const float4* gt4   = (const float4*)gt;
  float* buf0 = &scratch[0][wv][0];
  float* buf1 = &scratch[1][wv][0];

  // Prologue: groups G0, G1 (8 VMEM ops each: 6 DMA + lab + mk).
  dma_chunk(conf, buf0, b0, ln);
  int lab0 = labels[b0 + ln];        float mk0 = mask[b0 + ln];
  dma_chunk(conf, buf1, b0 + 64, ln);
  int lab1 = labels[b0 + 64 + ln];   float mk1 = mask[b0 + 64 + ln];

  float accm = 0.f, accp = 0.f, accr = 0.f;

  // c=0: queue G0(8),G1(8) -> wait all but 8 => G0 staged, G1 still flying.
  asm volatile("s_waitcnt vmcnt(8)" ::: "memory");
  do_chunk(buf0, ln, b0 + ln, lab0, mk0, pred4, gt4, keys, accm, accp, accr);
  asm volatile("s_waitcnt lgkmcnt(0)" ::: "memory");   // ds_reads done before overwrite
  dma_chunk(conf, buf0, b0 + 128, ln);
  int lab2 = labels[b0 + 128 + ln];  float mk2 = mask[b0 + 128 + ln];

  // c=1: queue G1(8),C0(<=3),G2(8) -> wait all but 8 => G1+C0 drained.
  asm volatile("s_waitcnt vmcnt(8)" ::: "memory");
  do_chunk(buf1, ln, b0 + 64 + ln, lab1, mk1, pred4, gt4, keys, accm, accp, accr);
  asm volatile("s_waitcnt lgkmcnt(0)" ::: "memory");
  dma_chunk(conf, buf1, b0 + 192, ln);
  int lab3 = labels[b0 + 192 + ln];  float mk3 = mask[b0 + 192 + ln];

  // c=2: queue G2(8),C1(<=3),G3(8) -> wait all but 8 => G2 staged.
  asm volatile("s_waitcnt vmcnt(8)" ::: "memory");
  do_chunk(buf0, ln, b0 + 128 + ln, lab2, mk2, pred4, gt4, keys, accm, accp, accr);

  // c=3: only G3(8) + C2 remain.
  asm volatile("s_waitcnt vmcnt(0)" ::: "memory");
  do_chunk(buf1, ln, b0 + 192 + ln, lab3, mk3, pred4, gt4, keys, accm, accp, accr);

  // Per-wave reduction; partials to ws (no barrier, no atomics).
  #pragma unroll
  for (int o = 32; o > 0; o >>= 1) {
    accm += __shfl_down(accm, o);
    accp += __shfl_down(accp, o);
    accr += __shfl_down(accr, o);
  }
  if (ln == 0) { pm[gw] = accm; pp[gw] = accp; pr[gw] = accr; }
}

// ---------------------------------------------------------------------------
// k_select: one block (512 threads) per batch row, keys register-resident.
// Exact k-th-largest key via MSB-first search, 2 bits per round (3 candidate
// thresholds, counts monotone) -> 16 barriers. Tie-exact top-k sum.
// ---------------------------------------------------------------------------
#define SEL_T 512
#define RPT   18                               // 8732 = 512*17 + 28

__global__ __launch_bounds__(SEL_T)
void k_select(const uint32_t* __restrict__ keys, double* __restrict__ neg)
{
  __shared__ int    slots[16 * 24 + 8];        // fresh region per round
  __shared__ int    ired[8];
  __shared__ double dred[8];
  const int tid  = threadIdx.x;
  const int w    = tid >> 6;
  const int lane = tid & 63;
  const uint32_t* row = keys + (size_t)blockIdx.x * PRI;

  uint32_t kr[RPT];
  #pragma unroll
  for (int r = 0; r < 17; ++r) kr[r] = row[tid + 512 * r];
  kr[17] = (tid < 28) ? row[tid + 8704] : 0u;  // pad 0: never >= any test (tests >= 2^31)

  // np = zero-key count (pad zeros excluded by tid<28 guard).
  int zc = 0;
  #pragma unroll
  for (int r = 0; r < 17; ++r) zc += (kr[r] == 0u) ? 1 : 0;
  if (tid < 28) zc += (kr[17] == 0u) ? 1 : 0;
  #pragma unroll
  for (int o = 32; o > 0; o >>= 1) zc += __shfl_down(zc, o);
  if (lane == 0) ired[w] = zc;
  __syncthreads();
  int np = 0;
  #pragma unroll
  for (int i = 0; i < 8; ++i) np += ired[i];   // uniform

  int k = np * NPR;
  const int nneg = PRI - np;
  if (k > nneg) k = nneg;

  double result = 0.0;
  if (k > 0) {                                 // uniform branch
    uint32_t cur = 0x80000000u;                // bit31 provably set: nneg >= k
    #pragma unroll 1
    for (int bit = 30; bit >= 1; bit -= 2) {
      const int rnd = (30 - bit) >> 1;
      const uint32_t tA = cur | (3u << (bit - 1));  // bits 11
      const uint32_t tB = cur | (1u << bit);        // bits 10
      const uint32_t tC = cur | (1u << (bit - 1));  // bits 01
      int cA = 0, cB = 0, cC = 0;
      #pragma unroll
      for (int r = 0; r < RPT; ++r) {
        cA += (int)__popcll(__ballot(kr[r] >= tA));
        cB += (int)__popcll(__ballot(kr[r] >= tB));
        cC += (int)__popcll(__ballot(kr[r] >= tC));
      }
      if (lane == 0) {
        int* sl = &slots[rnd * 24];
        sl[w] = cA; sl[8 + w] = cB; sl[16 + w] = cC;
      }
      __syncthreads();
      int TA = 0, TB = 0, TC = 0;
      const int* sl = &slots[rnd * 24];
      #pragma unroll
      for (int i = 0; i < 8; ++i) { TA += sl[i]; TB += sl[8 + i]; TC += sl[16 + i]; }
      cur = (TA >= k) ? tA : (TB >= k) ? tB : (TC >= k) ? tC : cur;  // largest v: count(>=v)>=k
    }
    {                                          // final bit 0
      const uint32_t t = cur | 1u;
      int c = 0;
      #pragma unroll
      for (int r = 0; r < RPT; ++r) c += (int)__popcll(__ballot(kr[r] >= t));
      if (lane == 0) slots[16 * 24 + w] = c;
      __syncthreads();
      int tot = 0;
      #pragma unroll
      for (int i = 0; i < 8; ++i) tot += slots[16 * 24 + i];
      if (tot >= k) cur = t;                   // cur == exact k-th largest key
    }

    const float thr = __uint_as_float(cur & 0x7fffffffu);
    double ssum = 0.0;
    int g = 0;
    #pragma unroll
    for (int r = 0; r < RPT; ++r) {
      if (kr[r] > cur) { ssum += (double)__uint_as_float(kr[r] & 0x7fffffffu); ++g; }
    }
    #pragma unroll
    for (int o = 32; o > 0; o >>= 1) { ssum += __shfl_down(ssum, o); g += __shfl_down(g, o); }
    if (lane == 0) { dred[w] = ssum; ired[w] = g; }
    __syncthreads();
    if (tid == 0) {
      double tot = 0.0; int gg = 0;
      #pragma unroll
      for (int i = 0; i < 8; ++i) { tot += dred[i]; gg += ired[i]; }
      result = tot + (double)(k - gg) * (double)thr;  // tied copies at threshold
    }
  }
  if (tid == 0) neg[blockIdx.x] = result;      // unconditional: ws is poisoned
}

// ---------------------------------------------------------------------------
// k_final: reduce per-wave partials (double accumulation) + write outputs.
// ---------------------------------------------------------------------------
__global__ __launch_bounds__(256)
void k_final(const float* __restrict__ pm, const float* __restrict__ pp,
             const float* __restrict__ pr, const double* __restrict__ neg,
             float* __restrict__ out)
{
  __shared__ double red[4][4];
  const int tid = threadIdx.x, w = tid >> 6, lane = tid & 63;
  double sm = 0.0, sp = 0.0, sr = 0.0, sn = 0.0;
  for (int i = tid; i < NWAVE; i += 256) {
    sm += (double)pm[i]; sp += (double)pp[i]; sr += (double)pr[i];
  }
  if (tid < BATCH) sn = neg[tid];
  #pragma unroll
  for (int o = 32; o > 0; o >>= 1) {
    sm += __shfl_down(sm, o); sp += __shfl_down(sp, o);
    sr += __shfl_down(sr, o); sn += __shfl_down(sn, o);
  }
  if (lane == 0) { red[0][w] = sm; red[1][w] = sp; red[2][w] = sr; red[3][w] = sn; }
  __syncthreads();
  if (tid == 0) {
    double m = 0, p = 0, r = 0, n = 0;
    #pragma unroll
    for (int i = 0; i < 4; ++i) { m += red[0][i]; p += red[1][i]; r += red[2][i]; n += red[3][i]; }
    out[0] = (float)(r / m);                   // regression_loss / all_batch_pos
    out[1] = (float)((p + n) / m);             // confidence_loss / all_batch_pos
  }
}

extern "C" void kernel_launch(void* const* d_in, const int* in_sizes, int n_in,
                              void* d_out, int out_size, void* d_ws, size_t ws_size,
                              hipStream_t stream) {
  const float* conf   = (const float*)d_in[0];
  const float* pred   = (const float*)d_in[1];
  const int*   labels = (const int*)d_in[2];
  const float* gt     = (const float*)d_in[3];
  const float* mask   = (const float*)d_in[4];
  float* out = (float*)d_out;

  char* ws = (char*)d_ws;
  const size_t keys_bytes = (size_t)TOTAL * sizeof(uint32_t);  // 4,470,784 (8-aligned)
  uint32_t* keys = (uint32_t*)ws;
  float*  pm  = (float*)(ws + keys_bytes);
  float*  pp  = pm + NWAVE;
  float*  pr  = pp + NWAVE;
  double* neg = (double*)(ws + keys_bytes +
                          (((size_t)3 * NWAVE * sizeof(float) + 7) & ~(size_t)7));

  k_main<<<GBLK, 256, 0, stream>>>(conf, pred, labels, gt, mask, keys, pm, pp, pr);
  k_select<<<BATCH, SEL_T, 0, stream>>>(keys, neg);
  k_final<<<1, 256, 0, stream>>>(pm, pp, pr, neg, out);
}